// Round 2
// baseline (716.073 us; speedup 1.0000x reference)
//
#include <hip/hip_runtime.h>
#include <math.h>

#define NJ 17
#define NP 14
#define NCH 59          // 17 + 3*14
#define BATCH 256
#define GRIDX (NJ + NP) // 31: 17 joint blocks + 14 pair blocks
#define TOTAL_BLOCKS (GRIDX * BATCH)

__constant__ int c_par0[NP] = {0, 1, 2, 0, 4, 5, 0, 8, 14, 15, 8, 11, 12, 8};
__constant__ int c_par1[NP] = {1, 2, 3, 4, 5, 6, 8, 14, 15, 16, 11, 12, 13, 10};

// Normalized gaussian heatmap: h(i,k) = exp(-0.25*((i-x)^2+(k-y)^2 - m))
// where m = min over integer grid of d2 (at the clamped rounded point),
// so h == g / max(g) in closed form (no grid max pass).
__device__ __forceinline__ void heat_params(const float* __restrict__ joint2d,
                                            int b, int j,
                                            float& x, float& y, float& m) {
    x = joint2d[(b * NJ + j) * 2 + 0] * 64.f;
    y = joint2d[(b * NJ + j) * 2 + 1] * 64.f;
    const float rx = fminf(fmaxf(floorf(x + 0.5f), 0.f), 63.f);
    const float ry = fminf(fmaxf(floorf(y + 0.5f), 0.f), 63.f);
    m = (rx - x) * (rx - x) + (ry - y) * (ry - y);
}

__device__ __forceinline__ float wave_reduce(float v) {
    #pragma unroll
    for (int off = 32; off; off >>= 1) v += __shfl_down(v, off, 64);
    return v;
}

// Grid (31, 256), 256 threads.
//  cb < 17 : L2D slice -> sum (h - m)^2 over 64x64
//  cb >= 17: whole pair (3 slices) -> (sqrt(S0)+sqrt(S1)+sqrt(S2))^2
//  cb == 0 : additionally folds in this batch row's l3d term
// Each block atomic-adds its pre-scaled double contribution; last block
// (ticket counter) writes the final scalar to out.
__global__ __launch_bounds__(256) void fused_loss_kernel(
    const float* __restrict__ pred,     // [B,17,3]
    const float* __restrict__ joints,   // [B,17,3]
    const float* __restrict__ middle,   // [B,59,64,64]
    const float* __restrict__ joint2d,  // [B,17,2]
    float* __restrict__ out,            // [1]
    double* __restrict__ acc,           // ws+0, zeroed by memset
    unsigned* __restrict__ counter)     // ws+8, zeroed by memset
{
    const int cb  = blockIdx.x;   // 0..30
    const int b   = blockIdx.y;   // 0..255
    const int tid = threadIdx.x;  // 0..255

    __shared__ float sred[4][3];
    float contrib = 0.f;

    if (cb < NJ) {
        // ---------- L2D slice ----------
        float x, y, msh;
        heat_params(joint2d, b, cb, x, y, msh);
        const float4* __restrict__ src =
            (const float4*)(middle + ((size_t)b * NCH + cb) * 4096);
        float S = 0.f;
        #pragma unroll
        for (int v = 0; v < 4; ++v) {
            const int idx  = tid + v * 256;
            const float4 m4 = src[idx];
            const int cell = idx * 4;           // 4 cells share a row
            const float fi = (float)(cell >> 6);
            const float k0 = (float)(cell & 63);
            const float mv[4] = {m4.x, m4.y, m4.z, m4.w};
            #pragma unroll
            for (int q = 0; q < 4; ++q) {
                const float dx = fi - x, dy = (k0 + (float)q) - y;
                const float h = __expf(-0.25f * (dx * dx + dy * dy - msh));
                const float d = h - mv[q];
                S += d * d;
            }
        }
        S = wave_reduce(S);
        if ((tid & 63) == 0) sred[tid >> 6][0] = S;
        __syncthreads();
        if (tid == 0)
            contrib = (0.005f / BATCH) *
                      (sred[0][0] + sred[1][0] + sred[2][0] + sred[3][0]);
    } else {
        // ---------- LHEM pair (3 slices in one block) ----------
        const int p  = cb - NJ;
        const int jp = c_par0[p], jc = c_par1[p];
        float xp, yp, mp, xc, yc, mc;
        heat_params(joint2d, b, jp, xp, yp, mp);
        heat_params(joint2d, b, jc, xc, yc, mc);
        const float dz = joints[(b * NJ + jp) * 3 + 2] -
                         (float)joints[(b * NJ + jc) * 3 + 2];
        const int r = (dz > 0.1f) ? 1 : ((fabsf(dz) < 0.1f) ? 0 : -1);
        const float wc0 = (r == -1) ? 1.f : 0.f;
        const float wc1 = (r ==  0) ? 1.f : 0.f;
        const float wc2 = (r ==  1) ? 1.f : 0.f;

        const float4* __restrict__ s0 =
            (const float4*)(middle + ((size_t)b * NCH + NJ + p * 3) * 4096);
        const float4* __restrict__ s1 = s0 + 1024;
        const float4* __restrict__ s2 = s0 + 2048;

        float S0 = 0.f, S1 = 0.f, S2 = 0.f;
        #pragma unroll
        for (int v = 0; v < 4; ++v) {
            const int idx = tid + v * 256;
            const float4 m0 = s0[idx];
            const float4 m1 = s1[idx];
            const float4 m2 = s2[idx];
            const int cell = idx * 4;
            const float fi = (float)(cell >> 6);
            const float k0 = (float)(cell & 63);
            const float a0[4] = {m0.x, m0.y, m0.z, m0.w};
            const float a1[4] = {m1.x, m1.y, m1.z, m1.w};
            const float a2[4] = {m2.x, m2.y, m2.z, m2.w};
            #pragma unroll
            for (int q = 0; q < 4; ++q) {
                const float fk = k0 + (float)q;
                const float dxp = fi - xp, dyp = fk - yp;
                const float hp = __expf(-0.25f * (dxp * dxp + dyp * dyp - mp));
                const float dxc = fi - xc, dyc = fk - yc;
                const float hc = __expf(-0.25f * (dxc * dxc + dyc * dyc - mc));
                const float d0 = wc0 * hc - a0[q];
                const float d1 = hp + wc1 * hc - a1[q];
                const float d2 = wc2 * hc - a2[q];
                S0 += d0 * d0; S1 += d1 * d1; S2 += d2 * d2;
            }
        }
        S0 = wave_reduce(S0); S1 = wave_reduce(S1); S2 = wave_reduce(S2);
        if ((tid & 63) == 0) {
            const int w = tid >> 6;
            sred[w][0] = S0; sred[w][1] = S1; sred[w][2] = S2;
        }
        __syncthreads();
        if (tid == 0) {
            const float t0 = sred[0][0] + sred[1][0] + sred[2][0] + sred[3][0];
            const float t1 = sred[0][1] + sred[1][1] + sred[2][1] + sred[3][1];
            const float t2 = sred[0][2] + sred[1][2] + sred[2][2] + sred[3][2];
            const float n = sqrtf(t0) + sqrtf(t1) + sqrtf(t2);
            contrib = (0.005f / BATCH) * n * n;
        }
    }

    // ---------- l3d for batch row b (one wave, cb==0 blocks only) ----------
    if (cb == 0 && tid < 64) {
        float v = 0.f;
        if (tid < NJ * 3) {
            const int i = b * NJ * 3 + tid;
            v = fabsf(joints[i] - pred[i]);
        }
        v = wave_reduce(v);
        if (tid == 0) contrib += v * (1.0f / BATCH);
    }

    // ---------- device-scope accumulate + last-block writeout ----------
    if (tid == 0) {
        atomicAdd(acc, (double)contrib);
        __threadfence();
        const unsigned old = atomicAdd(counter, 1u);
        if (old == (unsigned)(TOTAL_BLOCKS - 1)) {
            __threadfence();
            const double v = atomicAdd(acc, 0.0);  // atomic read of final value
            out[0] = (float)v;
        }
    }
}

extern "C" void kernel_launch(void* const* d_in, const int* in_sizes, int n_in,
                              void* d_out, int out_size, void* d_ws, size_t ws_size,
                              hipStream_t stream) {
    const float* pred    = (const float*)d_in[0];
    const float* joints  = (const float*)d_in[1];
    const float* middle  = (const float*)d_in[2];
    const float* joint2d = (const float*)d_in[3];
    float* out = (float*)d_out;

    double*   acc     = (double*)d_ws;
    unsigned* counter = (unsigned*)((char*)d_ws + 8);

    // ws is poisoned to 0xAA before every call — zero acc+counter (capture-legal).
    hipMemsetAsync(d_ws, 0, 16, stream);

    dim3 grid(GRIDX, BATCH);
    fused_loss_kernel<<<grid, 256, 0, stream>>>(pred, joints, middle, joint2d,
                                                out, acc, counter);
}

// Round 3
// 343.112 us; speedup vs baseline: 2.0870x; 2.0870x over previous
//
#include <hip/hip_runtime.h>
#include <math.h>

#define NJ 17
#define NP 14
#define NCH 59   // 17 + 3*14
#define BATCH 256

__constant__ int c_par0[NP] = {0, 1, 2, 0, 4, 5, 0, 8, 14, 15, 8, 11, 12, 8};
__constant__ int c_par1[NP] = {1, 2, 3, 4, 5, 6, 8, 14, 15, 16, 11, 12, 13, 10};

__device__ __forceinline__ float wave_reduce(float v) {
    #pragma unroll
    for (int off = 32; off; off >>= 1) v += __shfl_down(v, off, 64);
    return v;
}

// Normalized gaussian heatmap in closed form:
// h(i,k) = exp(-0.25*((i-x)^2+(k-y)^2 - m)), m = d2 at clamped nearest grid pt.
__device__ __forceinline__ void heat_params(const float* __restrict__ joint2d,
                                            int b, int j,
                                            float& x, float& y, float& m) {
    x = joint2d[(b * NJ + j) * 2 + 0] * 64.f;
    y = joint2d[(b * NJ + j) * 2 + 1] * 64.f;
    const float rx = fminf(fmaxf(floorf(x + 0.5f), 0.f), 63.f);
    const float ry = fminf(fmaxf(floorf(y + 0.5f), 0.f), 63.f);
    m = (rx - x) * (rx - x) + (ry - y) * (ry - y);
}

// One block per (b, c) slice. NO atomics, NO fences — pure read+reduce+store.
// partial[b*59 + c] = sum_cells (tgt - middle)^2
__global__ __launch_bounds__(256) void slice_sum_kernel(
    const float* __restrict__ joints,   // [B,17,3]
    const float* __restrict__ middle,   // [B,59,64,64]
    const float* __restrict__ joint2d,  // [B,17,2]
    float* __restrict__ partial)        // [B,59]
{
    const int c   = blockIdx.x;   // 0..58
    const int b   = blockIdx.y;   // 0..255
    const int tid = threadIdx.x;  // 0..255

    // ---- block-uniform target setup ----
    float wp = 0.f, wc = 0.f;
    int jp = 0, jc = 0;
    if (c < NJ) {
        jp = c; wp = 1.f;
    } else {
        const int pi = c - NJ;
        const int p  = pi / 3;
        const int ch = pi - p * 3;
        jp = c_par0[p];
        jc = c_par1[p];
        const float dz = joints[(b * NJ + jp) * 3 + 2] - joints[(b * NJ + jc) * 3 + 2];
        const int r = (dz > 0.1f) ? 1 : ((fabsf(dz) < 0.1f) ? 0 : -1);
        if (ch == 0)      { wp = 0.f; wc = (r == -1) ? 1.f : 0.f; }
        else if (ch == 1) { wp = 1.f; wc = (r ==  0) ? 1.f : 0.f; }
        else              { wp = 0.f; wc = (r ==  1) ? 1.f : 0.f; }
    }

    float xp = 0.f, yp = 0.f, mp = 0.f;
    float xq = 0.f, yq = 0.f, mq = 0.f;
    if (wp != 0.f) heat_params(joint2d, b, jp, xp, yp, mp);
    if (wc != 0.f) heat_params(joint2d, b, jc, xq, yq, mq);

    const float4* __restrict__ src =
        (const float4*)(middle + ((size_t)b * NCH + c) * 4096);

    float acc = 0.f;
    #pragma unroll
    for (int v = 0; v < 4; ++v) {
        const int idx  = tid + v * 256;      // float4 index 0..1023
        const float4 m4 = src[idx];
        const int cell = idx * 4;            // 4 cells share a row
        const float fi = (float)(cell >> 6);
        const float k0 = (float)(cell & 63);
        const float mv[4] = {m4.x, m4.y, m4.z, m4.w};
        #pragma unroll
        for (int q = 0; q < 4; ++q) {
            const float fk = k0 + (float)q;
            float tgt = 0.f;
            if (wp != 0.f) {  // block-uniform branch
                const float dx = fi - xp, dy = fk - yp;
                tgt += __expf(-0.25f * (dx * dx + dy * dy - mp));
            }
            if (wc != 0.f) {  // block-uniform branch
                const float dx = fi - xq, dy = fk - yq;
                tgt += __expf(-0.25f * (dx * dx + dy * dy - mq));
            }
            const float d = tgt - mv[q];
            acc += d * d;
        }
    }

    acc = wave_reduce(acc);
    __shared__ float sred[4];
    if ((tid & 63) == 0) sred[tid >> 6] = acc;
    __syncthreads();
    if (tid == 0)
        partial[b * NCH + c] = sred[0] + sred[1] + sred[2] + sred[3];
}

// 256 blocks (one per batch row) x 64 threads. Each block reduces its row's
// l3d + L2D + LHEM contribution, then ONE double atomic per block (256 total).
// Last block (ticket) writes the scalar out.
__global__ __launch_bounds__(64) void finalize_kernel(
    const float* __restrict__ pred,     // [B,17,3]
    const float* __restrict__ joints,   // [B,17,3]
    const float* __restrict__ partial,  // [B,59]
    float* __restrict__ out,            // [1]
    double* __restrict__ acc,           // ws2+0, zeroed by memset
    unsigned* __restrict__ counter)     // ws2+8, zeroed by memset
{
    const int b   = blockIdx.x;
    const int tid = threadIdx.x;

    float v = 0.f;
    // l3d row: 51 |diff| values
    if (tid < NJ * 3) {
        const int i = b * NJ * 3 + tid;
        v += fabsf(joints[i] - pred[i]);
    }
    // L2D row: 17 partials (scaled 0.005)
    if (tid < NJ)
        v += 0.005f * partial[b * NCH + tid];
    // LHEM row: 14 pairs (threads 17..30 to spread loads)
    if (tid >= NJ && tid < NJ + NP) {
        const float* s = partial + b * NCH + NJ + (tid - NJ) * 3;
        const float n = sqrtf(s[0]) + sqrtf(s[1]) + sqrtf(s[2]);
        v += 0.005f * n * n;
    }

    v = wave_reduce(v);
    if (tid == 0) {
        atomicAdd(acc, (double)v * (1.0 / BATCH));
        __threadfence();
        const unsigned old = atomicAdd(counter, 1u);
        if (old == BATCH - 1) {
            __threadfence();
            out[0] = (float)atomicAdd(acc, 0.0);  // atomic read of final value
        }
    }
}

extern "C" void kernel_launch(void* const* d_in, const int* in_sizes, int n_in,
                              void* d_out, int out_size, void* d_ws, size_t ws_size,
                              hipStream_t stream) {
    const float* pred    = (const float*)d_in[0];
    const float* joints  = (const float*)d_in[1];
    const float* middle  = (const float*)d_in[2];
    const float* joint2d = (const float*)d_in[3];
    float* out = (float*)d_out;

    float*    part    = (float*)d_ws;                         // B*59 floats
    double*   acc     = (double*)((char*)d_ws + 65536);       // 8 B
    unsigned* counter = (unsigned*)((char*)d_ws + 65536 + 8); // 4 B

    // zero only the 16-byte accumulator block (capture-legal)
    hipMemsetAsync((char*)d_ws + 65536, 0, 16, stream);

    dim3 grid(NCH, BATCH);
    slice_sum_kernel<<<grid, 256, 0, stream>>>(joints, middle, joint2d, part);
    finalize_kernel<<<BATCH, 64, 0, stream>>>(pred, joints, part, out, acc, counter);
}

// Round 4
// 334.871 us; speedup vs baseline: 2.1384x; 1.0246x over previous
//
#include <hip/hip_runtime.h>
#include <math.h>

#define NJ 17
#define NP 14
#define NCH 59     // 17 + 3*14
#define BATCH 256
#define PSTRIDE 64 // padded partial-row stride (floats) for aligned float4

__constant__ int c_par0[NP] = {0, 1, 2, 0, 4, 5, 0, 8, 14, 15, 8, 11, 12, 8};
__constant__ int c_par1[NP] = {1, 2, 3, 4, 5, 6, 8, 14, 15, 16, 11, 12, 13, 10};

__device__ __forceinline__ float wave_reduce(float v) {
    #pragma unroll
    for (int off = 32; off; off >>= 1) v += __shfl_down(v, off, 64);
    return v;
}

// Normalized heatmap h = exp(-0.25*(dx^2+dy^2-m)), m = d2 at clamped nearest
// integer grid point (== the grid max of the gaussian, closed form).
__device__ __forceinline__ void heat_params(const float* __restrict__ joint2d,
                                            int b, int j,
                                            float& x, float& y, float& m) {
    x = joint2d[(b * NJ + j) * 2 + 0] * 64.f;
    y = joint2d[(b * NJ + j) * 2 + 1] * 64.f;
    const float rx = fminf(fmaxf(floorf(x + 0.5f), 0.f), 63.f);
    const float ry = fminf(fmaxf(floorf(y + 0.5f), 0.f), 63.f);
    m = (rx - x) * (rx - x) + (ry - y) * (ry - y);
}

// One block per (b,c) slice. Separable gaussian: each thread's 4 columns are
// v-invariant (col0 = (4*tid)&63), rows are row0+16v -> 4 col-exps precomputed
// once + 1 row-exp per gaussian per v-iter. All 4 float4 loads issued as a
// batch before compute. c==0 blocks also fold in the batch row's l3d term.
__global__ __launch_bounds__(256) void slice_sum_kernel(
    const float* __restrict__ pred,     // [B,17,3]
    const float* __restrict__ joints,   // [B,17,3]
    const float* __restrict__ middle,   // [B,59,64,64]
    const float* __restrict__ joint2d,  // [B,17,2]
    float* __restrict__ partial)        // [B,PSTRIDE]: c=0..58 slices, 59=l3d row
{
    const int c   = blockIdx.x;   // 0..58
    const int b   = blockIdx.y;   // 0..255
    const int tid = threadIdx.x;  // 0..255

    // ---- issue the 4 slice loads immediately ----
    const float4* __restrict__ src =
        (const float4*)(middle + ((size_t)b * NCH + c) * 4096);
    float4 r0 = src[tid];
    float4 r1 = src[tid + 256];
    float4 r2 = src[tid + 512];
    float4 r3 = src[tid + 768];

    // ---- block-uniform target setup ----
    float wp = 0.f, wc = 0.f;
    int jp = 0, jc = 0;
    if (c < NJ) {
        jp = c; wp = 1.f;
    } else {
        const int pi = c - NJ;
        const int p  = pi / 3;
        const int ch = pi - p * 3;
        jp = c_par0[p];
        jc = c_par1[p];
        const float dz = joints[(b * NJ + jp) * 3 + 2] - joints[(b * NJ + jc) * 3 + 2];
        const int rsign = (dz > 0.1f) ? 1 : ((fabsf(dz) < 0.1f) ? 0 : -1);
        if (ch == 0)      { wp = 0.f; wc = (rsign == -1) ? 1.f : 0.f; }
        else if (ch == 1) { wp = 1.f; wc = (rsign ==  0) ? 1.f : 0.f; }
        else              { wp = 0.f; wc = (rsign ==  1) ? 1.f : 0.f; }
    }

    float xp = 0.f, yp = 0.f, mp = 0.f;
    float xq = 0.f, yq = 0.f, mq = 0.f;
    if (wp != 0.f) heat_params(joint2d, b, jp, xp, yp, mp);
    if (wc != 0.f) heat_params(joint2d, b, jc, xq, yq, mq);

    // ---- separable column exps (v-invariant: 4 fixed columns per thread) ----
    const float col0 = (float)((4 * tid) & 63);
    const int   row0 = (4 * tid) >> 6;           // 0..15
    float cEp[4] = {0.f, 0.f, 0.f, 0.f};
    float cEc[4] = {0.f, 0.f, 0.f, 0.f};
    if (wp != 0.f) {
        #pragma unroll
        for (int q = 0; q < 4; ++q) {
            const float dy = (col0 + (float)q) - yp;
            cEp[q] = __expf(-0.25f * dy * dy);
        }
    }
    if (wc != 0.f) {
        #pragma unroll
        for (int q = 0; q < 4; ++q) {
            const float dy = (col0 + (float)q) - yq;
            cEc[q] = __expf(-0.25f * dy * dy);
        }
    }
    const float mp4 = 0.25f * mp;
    const float mq4 = 0.25f * mq;

    const float4 rr[4] = {r0, r1, r2, r3};
    float acc = 0.f;
    #pragma unroll
    for (int v = 0; v < 4; ++v) {
        const float fi = (float)(row0 + 16 * v);
        float rEp = 0.f, rEc = 0.f;
        if (wp != 0.f) {  // block-uniform
            const float dx = fi - xp;
            rEp = __expf(fmaf(-0.25f * dx, dx, mp4));
        }
        if (wc != 0.f) {  // block-uniform
            const float dx = fi - xq;
            rEc = __expf(fmaf(-0.25f * dx, dx, mq4));
        }
        const float mv[4] = {rr[v].x, rr[v].y, rr[v].z, rr[v].w};
        #pragma unroll
        for (int q = 0; q < 4; ++q) {
            const float tgt = fmaf(rEc, cEc[q], rEp * cEp[q]);
            const float d = tgt - mv[q];
            acc = fmaf(d, d, acc);
        }
    }

    acc = wave_reduce(acc);
    __shared__ float sred[4];
    if ((tid & 63) == 0) sred[tid >> 6] = acc;
    __syncthreads();
    if (tid == 0)
        partial[b * PSTRIDE + c] = sred[0] + sred[1] + sred[2] + sred[3];

    // ---- l3d row (c==0 blocks, wave 0 only; 51 values) ----
    if (c == 0 && tid < 64) {
        float v = 0.f;
        if (tid < NJ * 3) {
            const int i = b * NJ * 3 + tid;
            v = fabsf(joints[i] - pred[i]);
        }
        v = wave_reduce(v);
        if (tid == 0) partial[b * PSTRIDE + 59] = v;
    }
}

// One block, 256 threads: thread b reduces batch row b (60 floats, 15 aligned
// float4 loads), then cross-thread double reduction. No atomics, no memset.
__global__ __launch_bounds__(256) void finalize_kernel(
    const float* __restrict__ partial,  // [B,PSTRIDE]
    float* __restrict__ out)            // [1]
{
    const int b = threadIdx.x;
    const float4* __restrict__ row = (const float4*)(partial + b * PSTRIDE);
    float4 r[15];
    #pragma unroll
    for (int i = 0; i < 15; ++i) r[i] = row[i];
    const float* pr = (const float*)r;

    float l2d = 0.f;
    #pragma unroll
    for (int c = 0; c < NJ; ++c) l2d += pr[c];

    float hem = 0.f;
    #pragma unroll
    for (int p = 0; p < NP; ++p) {
        const float n = sqrtf(pr[NJ + 3 * p + 0]) +
                        sqrtf(pr[NJ + 3 * p + 1]) +
                        sqrtf(pr[NJ + 3 * p + 2]);
        hem = fmaf(n, n, hem);
    }

    double v = ((double)pr[59] + 0.005 * ((double)l2d + (double)hem)) * (1.0 / BATCH);

    #pragma unroll
    for (int off = 32; off; off >>= 1) v += __shfl_down(v, off, 64);
    __shared__ double sh[4];
    if ((b & 63) == 0) sh[b >> 6] = v;
    __syncthreads();
    if (b == 0) out[0] = (float)(sh[0] + sh[1] + sh[2] + sh[3]);
}

extern "C" void kernel_launch(void* const* d_in, const int* in_sizes, int n_in,
                              void* d_out, int out_size, void* d_ws, size_t ws_size,
                              hipStream_t stream) {
    const float* pred    = (const float*)d_in[0];
    const float* joints  = (const float*)d_in[1];
    const float* middle  = (const float*)d_in[2];
    const float* joint2d = (const float*)d_in[3];
    float* out  = (float*)d_out;
    float* part = (float*)d_ws;   // BATCH*PSTRIDE floats, fully written before read

    dim3 grid(NCH, BATCH);
    slice_sum_kernel<<<grid, 256, 0, stream>>>(pred, joints, middle, joint2d, part);
    finalize_kernel<<<1, 256, 0, stream>>>(part, out);
}